// Round 13
// baseline (1583.164 us; speedup 1.0000x reference)
//
#include <hip/hip_runtime.h>

// ---------------- problem constants ----------------
#define NB    256
#define TLEN  1632
#define HIDC  64
#define CBD   512
#define NTOK  1024
#define T2L   816
#define T4L   408
#define MTOK  (NB*T4L)     // 104448
#define M2TOK (NB*T2L)     // 208896
#define MOUT  (NB*TLEN)    // 417792
#define TAU   0.05f

// d_out flat offsets (floats)
#define DO_OUT    ((size_t)0)
#define DO_RECON  ((size_t)417792)
#define DO_IDX    ((size_t)417795)
#define DO_QUANT  ((size_t)626691)

typedef unsigned short u16;
typedef unsigned long long u64;
typedef __attribute__((ext_vector_type(8))) short short8;
typedef __attribute__((ext_vector_type(4))) float f32x4;

// ---------------- workspace layout (float units) ----------------
static constexpr size_t OFF_XR  = 0;                         // MTOK*512 f32
static constexpr size_t OFF_H1  = OFF_XR + (size_t)MTOK*512;
static constexpr size_t OFF_H2  = OFF_H1 + (size_t)NB*T2L*64;
static constexpr size_t OFF_BE2 = OFF_H2 + (size_t)NB*T4L*64;
static constexpr size_t OFF_BD1 = OFF_BE2 + 8192;
static constexpr size_t OFF_BD2 = OFF_BD1 + 65536;
static constexpr size_t OFF_BX1 = OFF_BD2 + 8192;
static constexpr size_t OFF_BX2 = OFF_BX1 + 128;
static constexpr size_t OFF_ZB  = OFF_BX2 + 128;
static constexpr size_t OFF_C2  = OFF_ZB + 128;
static constexpr size_t OFF_SLOT= OFF_C2 + 2048;             // 1536 loss slots
static constexpr size_t OFF_IDXI= OFF_SLOT + 1536;
static constexpr size_t OFF_KEYS= OFF_IDXI + (size_t)MTOK*2;
static constexpr size_t OFF_FC  = OFF_KEYS + (size_t)MTOK*4;
static constexpr size_t OFF_FLAG= OFF_FC + 4;
static constexpr size_t OFF_CBH = OFF_FLAG + (size_t)MTOK*2; // 2048*512 u16
static constexpr size_t OFF_CBL = OFF_CBH + 524288;
static constexpr size_t OFF_P0  = OFF_CBL + 524288;
static constexpr size_t OFF_P1  = OFF_P0 + 131072;
static constexpr size_t OFF_PAIRS = OFF_P1 + 131072;         // MTOK*8 u64

// ---------------- helpers ----------------
__device__ inline u64 shfl_xor_u64_w16(u64 v, int m) {
    unsigned lo = (unsigned)v, hi = (unsigned)(v >> 32);
    lo = __shfl_xor(lo, m, 16);
    hi = __shfl_xor(hi, m, 16);
    return (((u64)hi) << 32) | lo;
}
__device__ inline u64 packkey(float d, int n) {
    unsigned u = __float_as_uint(d);
    u = (u & 0x80000000u) ? ~u : (u | 0x80000000u);
    return (((u64)u) << 32) | (unsigned)n;
}
__device__ inline float unpackd(u64 k) {
    unsigned u = (unsigned)(k >> 32);
    u = (u & 0x80000000u) ? (u & 0x7fffffffu) : ~u;
    return __uint_as_float(u);
}
__device__ inline void merge2(u64& k1, u64& k2, u64 o1, u64 o2) {
    u64 n1 = (k1 < o1) ? k1 : o1;
    u64 hi = (k1 < o1) ? o1 : k1;
    u64 cand = (k1 <= o1) ? k2 : o2;
    u64 n2 = (hi < cand) ? hi : cand;
    k1 = n1; k2 = n2;
}
__device__ inline void split4(float4 v, uint2& h, uint2& l) {
    unsigned b0 = __float_as_uint(v.x), b1 = __float_as_uint(v.y),
             b2 = __float_as_uint(v.z), b3 = __float_as_uint(v.w);
    float l0 = v.x - __uint_as_float(b0 & 0xFFFF0000u);
    float l1 = v.y - __uint_as_float(b1 & 0xFFFF0000u);
    float l2 = v.z - __uint_as_float(b2 & 0xFFFF0000u);
    float l3 = v.w - __uint_as_float(b3 & 0xFFFF0000u);
    h.x = (b0 >> 16) | (b1 & 0xFFFF0000u);
    h.y = (b2 >> 16) | (b3 & 0xFFFF0000u);
    l.x = (__float_as_uint(l0) >> 16) | (__float_as_uint(l1) & 0xFFFF0000u);
    l.y = (__float_as_uint(l2) >> 16) | (__float_as_uint(l3) & 0xFFFF0000u);
}

// ---------------- fused setup: weight prep + codebook split + codebook norms ----------------
__global__ void setup_kernel(const float* __restrict__ We2, const float* __restrict__ Wtd1,
                             const float* __restrict__ Wtd2, const float* __restrict__ bd1,
                             const float* __restrict__ bd2, const float* __restrict__ cbs,
                             float* __restrict__ Be2, float* __restrict__ Bd1,
                             float* __restrict__ Bd2, float* __restrict__ bx1, float* __restrict__ bx2,
                             u16* __restrict__ cbh, u16* __restrict__ cbl, float* __restrict__ c2) {
    size_t t = (size_t)blockIdx.x * 256 + threadIdx.x;   // grid 1024 -> 262144 threads
    {
        float4 v = *(const float4*)(cbs + t * 4);
        uint2 h, l; split4(v, h, l);
        *(uint2*)&cbh[t * 4] = h;
        *(uint2*)&cbl[t * 4] = l;
    }
    {
        int w = (int)(t >> 6);
        int lane = threadIdx.x & 63;
        if (w < 2048) {
            const float* r = cbs + (size_t)w * 512;
            float4 a = *(const float4*)(r + lane * 8);
            float4 b = *(const float4*)(r + lane * 8 + 4);
            float s = a.x*a.x + a.y*a.y + a.z*a.z + a.w*a.w + b.x*b.x + b.y*b.y + b.z*b.z + b.w*b.w;
            #pragma unroll
            for (int o = 32; o > 0; o >>= 1) s += __shfl_down(s, o, 64);
            if (lane == 0) c2[w] = s;
        }
    }
    size_t stride = (size_t)gridDim.x * 256;
    for (size_t x = t; x < 64 * 128; x += stride) {
        int c = (int)(x >> 7), k = (int)(x & 127);
        Be2[x] = We2[c * 128 + ((k & 63) << 1) + (k >> 6)];
    }
    for (size_t x = t; x < 128 * 512; x += stride) {
        int n = (int)(x >> 9), k = (int)(x & 511);
        Bd1[x] = Wtd1[k * 128 + n];
    }
    for (size_t x = t; x < 128 * 64; x += stride) {
        int n = (int)(x >> 6), k = (int)(x & 63);
        Bd2[x] = Wtd2[k * 128 + n];
    }
    for (size_t x = t; x < 128; x += stride) { bx1[x] = bd1[x >> 1]; bx2[x] = bd2[x >> 1]; }
}

// ---------------- encoder conv1 ----------------
__global__ void enc1_kernel(const float* __restrict__ img, const float* __restrict__ W,
                            const float* __restrict__ bias, float* __restrict__ h1) {
    int idx = blockIdx.x * 256 + threadIdx.x;
    int c = idx & 63;
    int t = (idx >> 6) % T2L;
    int b = idx / (64 * T2L);
    float v = W[c * 2] * img[(size_t)b * TLEN + 2 * t] +
              W[c * 2 + 1] * img[(size_t)b * TLEN + 2 * t + 1] + bias[c];
    h1[idx] = fmaxf(v, 0.f);
}

// ---------------- generic NT SGEMM (cmode0 only) ----------------
__global__ __launch_bounds__(256) void gemm_nt(const float* __restrict__ A, const float* __restrict__ Bw,
                        const float* __restrict__ bias, float* __restrict__ C,
                        int M, int N, int K, int amode, int relu) {
    __shared__ float As[32][132];
    __shared__ float Bs[32][68];
    int m0 = blockIdx.x * 128;
    int n0 = blockIdx.y * 64;
    int tid = threadIdx.x;
    int tx = tid & 15;
    int ty = tid >> 4;
    float acc[8][4];
    #pragma unroll
    for (int i = 0; i < 8; ++i)
        #pragma unroll
        for (int j = 0; j < 4; ++j) acc[i][j] = 0.f;

    for (int k0 = 0; k0 < K; k0 += 32) {
        #pragma unroll
        for (int i = 0; i < 4; ++i) {
            int idx = tid + i * 256;
            int row = idx >> 3;
            int kq = idx & 7;
            int m = m0 + row;
            size_t base;
            if (amode == 0) base = (size_t)m * K;
            else            base = (size_t)(((m / T4L) * T2L + 2 * (m % T4L)) * 64);
            float4 v = *(const float4*)(A + base + k0 + kq * 4);
            int kk = kq * 4;
            As[kk + 0][row] = v.x; As[kk + 1][row] = v.y;
            As[kk + 2][row] = v.z; As[kk + 3][row] = v.w;
        }
        #pragma unroll
        for (int i = 0; i < 2; ++i) {
            int idx = tid + i * 256;
            int row = idx >> 3;
            int kq = idx & 7;
            float4 v = *(const float4*)(Bw + (size_t)(n0 + row) * K + k0 + kq * 4);
            int kk = kq * 4;
            Bs[kk + 0][row] = v.x; Bs[kk + 1][row] = v.y;
            Bs[kk + 2][row] = v.z; Bs[kk + 3][row] = v.w;
        }
        __syncthreads();
        #pragma unroll
        for (int kk = 0; kk < 32; ++kk) {
            float a[8], bf[4];
            float4 a0 = *(const float4*)&As[kk][ty * 8];
            float4 a1 = *(const float4*)&As[kk][ty * 8 + 4];
            a[0]=a0.x; a[1]=a0.y; a[2]=a0.z; a[3]=a0.w;
            a[4]=a1.x; a[5]=a1.y; a[6]=a1.z; a[7]=a1.w;
            float4 b0 = *(const float4*)&Bs[kk][tx * 4];
            bf[0]=b0.x; bf[1]=b0.y; bf[2]=b0.z; bf[3]=b0.w;
            #pragma unroll
            for (int i = 0; i < 8; ++i)
                #pragma unroll
                for (int j = 0; j < 4; ++j) acc[i][j] += a[i] * bf[j];
        }
        __syncthreads();
    }
    #pragma unroll
    for (int i = 0; i < 8; ++i) {
        int m = m0 + ty * 8 + i;
        float4 v;
        v.x = acc[i][0] + bias[n0 + tx * 4 + 0];
        v.y = acc[i][1] + bias[n0 + tx * 4 + 1];
        v.z = acc[i][2] + bias[n0 + tx * 4 + 2];
        v.w = acc[i][3] + bias[n0 + tx * 4 + 3];
        if (relu) { v.x=fmaxf(v.x,0.f); v.y=fmaxf(v.y,0.f); v.z=fmaxf(v.z,0.f); v.w=fmaxf(v.w,0.f); }
        *(float4*)(C + (size_t)m * N + n0 + tx * 4) = v;
    }
}

// ---------------- VQ: block 128(M)x256(N), wave 64x128, split-bf16 MFMA, rr=0 ----------------
// Q1=0: plain A staging (no gather code/registers). Q1=1: A = xr - cb0[i0] on the fly.
// launch_bounds (256,2): ~220-VGPR working set; (256,3) spills (R10: 3GB scratch).
template<int Q1>
__global__ __launch_bounds__(256, 2) void vq_bf16_top2(
    const float* __restrict__ A, const u16* __restrict__ cbh, const u16* __restrict__ cbl,
    const float* __restrict__ c2, const u64* __restrict__ prevkeys, const float* __restrict__ cb0,
    u64* __restrict__ pairs)
{
    __shared__ u16 Ah[128 * 40], Al[128 * 40];
    __shared__ u16 Bh[256 * 40], Bl[256 * 40];
    int tid = threadIdx.x;
    int n0 = blockIdx.x * 256, m0 = blockIdx.y * 128;
    int lane = tid & 63, wid = tid >> 6;
    int lm = lane & 15, quad = lane >> 4;
    int wm = wid >> 1, wn = wid & 1;

    f32x4 acc[4][8];
    #pragma unroll
    for (int i = 0; i < 4; ++i)
        #pragma unroll
        for (int j = 0; j < 8; ++j) acc[i][j] = (f32x4){0.f, 0.f, 0.f, 0.f};

    int ar[4], acq[4];
    size_t coff[4];
    #pragma unroll
    for (int i = 0; i < 4; ++i) {
        int idx = tid + i * 256;
        ar[i] = idx >> 3; acq[i] = idx & 7;
        if (Q1) {
            int i0 = (int)(prevkeys[m0 + ar[i]] & 0xFFFFFFFFull);
            coff[i] = (size_t)i0 * 512;
        }
    }

    for (int k0 = 0; k0 < 512; k0 += 32) {
        float4 av[4];
        #pragma unroll
        for (int i = 0; i < 4; ++i) {
            av[i] = *(const float4*)(A + (size_t)(m0 + ar[i]) * 512 + k0 + acq[i] * 4);
            if (Q1) {
                float4 cv = *(const float4*)(cb0 + coff[i] + k0 + acq[i] * 4);
                av[i].x -= cv.x; av[i].y -= cv.y; av[i].z -= cv.z; av[i].w -= cv.w;
            }
        }
        short8 bv[8];
        int br[8], bcc[8], bpl[8];
        #pragma unroll
        for (int i = 0; i < 8; ++i) {
            int idx = tid + i * 256;
            br[i] = idx >> 3; int sub = idx & 7;
            bcc[i] = sub & 3; bpl[i] = sub >> 2;
            const u16* src = bpl[i] ? cbl : cbh;
            bv[i] = *(const short8*)(src + (size_t)(n0 + br[i]) * 512 + k0 + bcc[i] * 8);
        }
        __syncthreads();
        #pragma unroll
        for (int i = 0; i < 4; ++i) {
            uint2 h, l; split4(av[i], h, l);
            *(uint2*)&Ah[ar[i] * 40 + acq[i] * 4] = h;
            *(uint2*)&Al[ar[i] * 40 + acq[i] * 4] = l;
        }
        #pragma unroll
        for (int i = 0; i < 8; ++i) {
            u16* dst = bpl[i] ? Bl : Bh;
            *(short8*)&dst[br[i] * 40 + bcc[i] * 8] = bv[i];
        }
        __syncthreads();
        short8 ah[4], al_[4];
        #pragma unroll
        for (int mt = 0; mt < 4; ++mt) {
            int r = wm * 64 + mt * 16 + lm;
            ah[mt]  = *(const short8*)&Ah[r * 40 + quad * 8];
            al_[mt] = *(const short8*)&Al[r * 40 + quad * 8];
        }
        #pragma unroll
        for (int nt = 0; nt < 8; ++nt) {
            int rn = wn * 128 + nt * 16 + lm;
            short8 bh = *(const short8*)&Bh[rn * 40 + quad * 8];
            short8 bl = *(const short8*)&Bl[rn * 40 + quad * 8];
            #pragma unroll
            for (int mt = 0; mt < 4; ++mt) {
                acc[mt][nt] = __builtin_amdgcn_mfma_f32_16x16x32_bf16(al_[mt], bh, acc[mt][nt], 0, 0, 0);
                acc[mt][nt] = __builtin_amdgcn_mfma_f32_16x16x32_bf16(ah[mt], bl, acc[mt][nt], 0, 0, 0);
                acc[mt][nt] = __builtin_amdgcn_mfma_f32_16x16x32_bf16(ah[mt], bh, acc[mt][nt], 0, 0, 0);
            }
        }
    }
    float c2v[8];
    #pragma unroll
    for (int nt = 0; nt < 8; ++nt) c2v[nt] = c2[n0 + wn * 128 + nt * 16 + lm];

    __syncthreads();
    u64* scr = (u64*)Ah;   // [2 wn][128 tokens][2]
    #pragma unroll
    for (int mt = 0; mt < 4; ++mt) {
        #pragma unroll
        for (int rg = 0; rg < 4; ++rg) {
            int tl = wm * 64 + mt * 16 + quad * 4 + rg;
            u64 k1 = ~0ull, k2 = ~0ull;
            #pragma unroll
            for (int nt = 0; nt < 8; ++nt) {
                float d = c2v[nt] - 2.0f * acc[mt][nt][rg];
                u64 k = packkey(d, n0 + wn * 128 + nt * 16 + lm);
                if (k < k1) { k2 = k1; k1 = k; } else if (k < k2) { k2 = k; }
            }
            #pragma unroll
            for (int s = 1; s < 16; s <<= 1) {
                u64 o1 = shfl_xor_u64_w16(k1, s);
                u64 o2 = shfl_xor_u64_w16(k2, s);
                merge2(k1, k2, o1, o2);
            }
            if (lm == 0) { scr[wn * 256 + tl * 2] = k1; scr[wn * 256 + tl * 2 + 1] = k2; }
        }
    }
    __syncthreads();
    if (tid < 128) {
        u64 a1 = scr[tid * 2], a2 = scr[tid * 2 + 1];
        merge2(a1, a2, scr[256 + tid * 2], scr[256 + tid * 2 + 1]);
        size_t base = (size_t)(m0 + tid) * 8 + blockIdx.x * 2;
        pairs[base] = a1; pairs[base + 1] = a2;
    }
}

// ---------------- reduce: global top2 per token from 4 block-pairs ----------------
__global__ void vq_reduce(const u64* __restrict__ pairs, u64* __restrict__ keybuf,
                          int* __restrict__ fc, int* __restrict__ flaglist) {
    int m = blockIdx.x * 256 + threadIdx.x;
    const u64* p = pairs + (size_t)m * 8;
    u64 k1 = ~0ull, k2 = ~0ull;
    #pragma unroll
    for (int i = 0; i < 8; ++i) {
        u64 k = p[i];
        if (k < k1) { k2 = k1; k1 = k; } else if (k < k2) { k2 = k; }
    }
    keybuf[m] = k1;
    if (unpackd(k2) - unpackd(k1) < TAU) {
        int pos = atomicAdd(fc, 1);
        flaglist[pos] = m;
    }
}

// ---------------- rescue: exact fp32 argmin for flagged tokens (rr=0; q1 subtracts cb0[i0]) ----
__global__ void vq_rescue(const float* __restrict__ xr, const float* __restrict__ cb,
                          const float* __restrict__ c2, const float* __restrict__ cb0,
                          const u64* __restrict__ prevkeys,
                          const int* __restrict__ fc, const int* __restrict__ flaglist,
                          u64* __restrict__ keybuf) {
    __shared__ u64 red[4];
    int cnt = *fc;
    int lane = threadIdx.x & 63, wid = threadIdx.x >> 6;
    for (int f = blockIdx.x; f < cnt; f += gridDim.x) {
        int m = flaglist[f];
        float4 rv0 = *(const float4*)(xr + (size_t)m * 512 + lane * 8);
        float4 rv1 = *(const float4*)(xr + (size_t)m * 512 + lane * 8 + 4);
        if (cb0) {
            size_t co = (size_t)(prevkeys[m] & 0xFFFFFFFFull) * 512;
            float4 c0 = *(const float4*)(cb0 + co + lane * 8);
            float4 c1 = *(const float4*)(cb0 + co + lane * 8 + 4);
            rv0.x -= c0.x; rv0.y -= c0.y; rv0.z -= c0.z; rv0.w -= c0.w;
            rv1.x -= c1.x; rv1.y -= c1.y; rv1.z -= c1.z; rv1.w -= c1.w;
        }
        u64 best = ~0ull;
        for (int c = wid * 256; c < wid * 256 + 256; ++c) {
            const float* cp = cb + (size_t)c * 512 + lane * 8;
            float4 c0 = *(const float4*)cp;
            float4 c1 = *(const float4*)(cp + 4);
            float p = rv0.x*c0.x + rv0.y*c0.y + rv0.z*c0.z + rv0.w*c0.w
                    + rv1.x*c1.x + rv1.y*c1.y + rv1.z*c1.z + rv1.w*c1.w;
            #pragma unroll
            for (int s = 1; s < 64; s <<= 1) p += __shfl_xor(p, s, 64);
            u64 k = packkey(c2[c] - 2.0f * p, c);
            if (k < best) best = k;
        }
        if (lane == 0) red[wid] = best;
        __syncthreads();
        if (threadIdx.x == 0) {
            u64 b = red[0];
            if (red[1] < b) b = red[1];
            if (red[2] < b) b = red[2];
            if (red[3] < b) b = red[3];
            keybuf[m] = b;
        }
        __syncthreads();
    }
}

// ---------------- fused post-VQ: indices + commit losses + quantized output + d1 ----------------
// grid (NB, 7, 4): 64 tokens x 128 channels per block. bz==0 also writes idx + d1.
__global__ __launch_bounds__(256) void post_vq(
    const float* __restrict__ xr, const float* __restrict__ cb0f, const float* __restrict__ cb1f,
    const u64* __restrict__ keys0, const u64* __restrict__ keys1,
    const float* __restrict__ P0, const float* __restrict__ P1, const float* __restrict__ bx1,
    float* __restrict__ idx_f, int* __restrict__ idx_i,
    float* __restrict__ qout, float* __restrict__ d1, float* __restrict__ slots)
{
    __shared__ float buf[64][129];
    __shared__ int i0s[64], i1s[64];
    __shared__ float reds[8];
    int b = blockIdx.x;
    int t0 = blockIdx.y * 64;
    int c0 = blockIdx.z * 128;
    int tid = threadIdx.x;
    if (tid < 64) {
        int t = t0 + tid;
        int i0 = 0, i1 = 0;
        if (t < T4L) {
            int m = b * T4L + t;
            i0 = (int)(keys0[m] & 0xFFFFFFFFull);
            i1 = (int)(keys1[m] & 0xFFFFFFFFull);
            if (blockIdx.z == 0) {
                idx_f[(size_t)m * 2]     = (float)i0;
                idx_f[(size_t)m * 2 + 1] = (float)i1;
                idx_i[m * 2] = i0;
                idx_i[m * 2 + 1] = i1;
            }
        }
        i0s[tid] = i0; i1s[tid] = i1;
    }
    __syncthreads();
    // gather + commit partials + stage for transpose
    int cl = tid & 127, th = tid >> 7;
    float s1 = 0.f, s2 = 0.f;
    for (int t = th; t < 64; t += 2) {
        if (t0 + t < T4L) {
            int m = b * T4L + t0 + t;
            float v0 = cb0f[(size_t)i0s[t] * 512 + c0 + cl];
            float v1 = cb1f[(size_t)i1s[t] * 512 + c0 + cl];
            float x  = xr[(size_t)m * 512 + c0 + cl];
            float sum = v0 + v1;
            buf[t][cl] = sum;
            float e1 = x - v0, e2 = x - sum;
            s1 += e1 * e1; s2 += e2 * e2;
        }
    }
    // per-wave reduce, then 4 atomics each
    #pragma unroll
    for (int o = 32; o > 0; o >>= 1) { s1 += __shfl_down(s1, o, 64); s2 += __shfl_down(s2, o, 64); }
    int lane = tid & 63, wv = tid >> 6;
    if (lane == 0) { reds[wv] = s1; reds[4 + wv] = s2; }
    __syncthreads();
    if (tid == 0) {
        int slot = (b * 7 + blockIdx.y) & 511;
        atomicAdd(&slots[512 + slot],  reds[0] + reds[1] + reds[2] + reds[3]);
        atomicAdd(&slots[1024 + slot], reds[4] + reds[5] + reds[6] + reds[7]);
    }
    // transpose-write quantized (channel-major)
    int ch = tid >> 6;
    for (int cc = ch; cc < 128; cc += 4) {
        int t = t0 + lane;
        if (t < T4L) qout[((size_t)b * 512 + c0 + cc) * T4L + t] = buf[lane][cc];
    }
    // d1 from code tables (bz==0 only)
    if (blockIdx.z == 0) {
        for (int x = tid; x < 64 * 128; x += 256) {
            int n = x & 127, tl = x >> 7;
            int t = t0 + tl;
            if (t < T4L) {
                float v = P0[i0s[tl] * 128 + n] + P1[i1s[tl] * 128 + n] + bx1[n];
                v = fmaxf(v, 0.f);
                d1[((size_t)(b * T2L + 2 * t + (n & 1))) * 64 + (n >> 1)] = v;
            }
        }
    }
}

// ---------------- fused convT2 + final 1x1 conv + recon loss ----------------
__global__ __launch_bounds__(256) void dec2_fused(
    const float* __restrict__ d1, const float* __restrict__ Bd2, const float* __restrict__ bx2,
    const float* __restrict__ W3, const float* __restrict__ b3, const float* __restrict__ img,
    float* __restrict__ out, float* __restrict__ slots)
{
    __shared__ float As[32][132];
    __shared__ float Bs[32][132];
    __shared__ float w3s[64];
    int m0 = blockIdx.x * 128;
    int tid = threadIdx.x;
    int tx = tid & 15;
    int ty = tid >> 4;
    if (tid < 64) w3s[tid] = W3[tid];
    float acc[8][8];
    #pragma unroll
    for (int i = 0; i < 8; ++i)
        #pragma unroll
        for (int j = 0; j < 8; ++j) acc[i][j] = 0.f;

    for (int k0 = 0; k0 < 64; k0 += 32) {
        #pragma unroll
        for (int i = 0; i < 4; ++i) {
            int idx = tid + i * 256;
            int row = idx >> 3;
            int kq = idx & 7;
            float4 v = *(const float4*)(d1 + (size_t)(m0 + row) * 64 + k0 + kq * 4);
            int kk = kq * 4;
            As[kk + 0][row] = v.x; As[kk + 1][row] = v.y;
            As[kk + 2][row] = v.z; As[kk + 3][row] = v.w;
        }
        #pragma unroll
        for (int i = 0; i < 4; ++i) {
            int idx = tid + i * 256;
            int row = idx >> 3;
            int kq = idx & 7;
            float4 v = *(const float4*)(Bd2 + (size_t)row * 64 + k0 + kq * 4);
            int kk = kq * 4;
            Bs[kk + 0][row] = v.x; Bs[kk + 1][row] = v.y;
            Bs[kk + 2][row] = v.z; Bs[kk + 3][row] = v.w;
        }
        __syncthreads();
        #pragma unroll
        for (int kk = 0; kk < 32; ++kk) {
            float a[8], bf[8];
            float4 a0 = *(const float4*)&As[kk][ty * 8];
            float4 a1 = *(const float4*)&As[kk][ty * 8 + 4];
            a[0]=a0.x; a[1]=a0.y; a[2]=a0.z; a[3]=a0.w;
            a[4]=a1.x; a[5]=a1.y; a[6]=a1.z; a[7]=a1.w;
            float4 b0 = *(const float4*)&Bs[kk][tx * 4];
            float4 b1 = *(const float4*)&Bs[kk][64 + tx * 4];
            bf[0]=b0.x; bf[1]=b0.y; bf[2]=b0.z; bf[3]=b0.w;
            bf[4]=b1.x; bf[5]=b1.y; bf[6]=b1.z; bf[7]=b1.w;
            #pragma unroll
            for (int i = 0; i < 8; ++i)
                #pragma unroll
                for (int j = 0; j < 8; ++j) acc[i][j] += a[i] * bf[j];
        }
        __syncthreads();
    }
    float bb3 = b3[0];
    float local = 0.f;
    #pragma unroll
    for (int i = 0; i < 8; ++i) {
        float s0 = 0.f, s1 = 0.f;
        #pragma unroll
        for (int j = 0; j < 4; ++j) {
            int n = tx * 4 + j;
            float v = fmaxf(acc[i][j] + bx2[n], 0.f);
            float w = w3s[n >> 1];
            if (j & 1) s1 += w * v; else s0 += w * v;
            int n2 = 64 + tx * 4 + j;
            float v2 = fmaxf(acc[i][j + 4] + bx2[n2], 0.f);
            float w2 = w3s[n2 >> 1];
            if (j & 1) s1 += w2 * v2; else s0 += w2 * v2;
        }
        #pragma unroll
        for (int o = 8; o > 0; o >>= 1) { s0 += __shfl_down(s0, o, 16); s1 += __shfl_down(s1, o, 16); }
        if (tx == 0) {
            int m = m0 + ty * 8 + i;
            int b = m / T2L, t2 = m % T2L;
            size_t o0 = (size_t)b * TLEN + 2 * t2;
            float v0 = s0 + bb3, v1 = s1 + bb3;
            out[o0] = v0; out[o0 + 1] = v1;
            float e0 = img[o0] - v0, e1 = img[o0 + 1] - v1;
            local += e0 * e0 + e1 * e1;
        }
    }
    if (tx == 0) atomicAdd(&slots[(blockIdx.x * 16 + ty) & 511], local);
}

// ---------------- finalize losses ----------------
__global__ void finalize_kernel(const float* __restrict__ slots, float* __restrict__ out_scalars) {
    __shared__ float red[256];
    int tid = threadIdx.x;
    for (int which = 0; which < 3; ++which) {
        float s = slots[which * 512 + tid] + slots[which * 512 + tid + 256];
        red[tid] = s; __syncthreads();
        for (int st = 128; st > 0; st >>= 1) { if (tid < st) red[tid] += red[tid + st]; __syncthreads(); }
        if (tid == 0) {
            float denom = (which == 0) ? (float)MOUT : (float)((size_t)MTOK * 512);
            out_scalars[which] = red[0] / denom;
        }
        __syncthreads();
    }
}

// ---------------- launch ----------------
extern "C" void kernel_launch(void* const* d_in, const int* in_sizes, int n_in,
                              void* d_out, int out_size, void* d_ws, size_t ws_size,
                              hipStream_t stream) {
    const float* img  = (const float*)d_in[0];
    const float* We1  = (const float*)d_in[1];
    const float* be1  = (const float*)d_in[2];
    const float* We2  = (const float*)d_in[3];
    const float* be2  = (const float*)d_in[4];
    const float* We3  = (const float*)d_in[5];
    const float* be3  = (const float*)d_in[6];
    const float* cbs  = (const float*)d_in[7];
    const float* Wtd1 = (const float*)d_in[8];
    const float* bd1  = (const float*)d_in[9];
    const float* Wtd2 = (const float*)d_in[10];
    const float* bd2  = (const float*)d_in[11];
    const float* Wd3  = (const float*)d_in[12];
    const float* bd3  = (const float*)d_in[13];

    float* w = (float*)d_ws;
    float* xr   = w + OFF_XR;
    float* h1   = w + OFF_H1;
    float* h2   = w + OFF_H2;
    float* Be2  = w + OFF_BE2;
    float* Bd1  = w + OFF_BD1;
    float* Bd2  = w + OFF_BD2;
    float* bx1  = w + OFF_BX1;
    float* bx2  = w + OFF_BX2;
    float* zerob= w + OFF_ZB;
    float* c2   = w + OFF_C2;
    float* slots= w + OFF_SLOT;
    int*   idxi = (int*)(w + OFF_IDXI);
    u64*   keys = (u64*)(w + OFF_KEYS);
    int*   fc   = (int*)(w + OFF_FC);
    int*   flag = (int*)(w + OFF_FLAG);
    u16*   cbh  = (u16*)(w + OFF_CBH);
    u16*   cbl  = (u16*)(w + OFF_CBL);
    float* P0   = w + OFF_P0;
    float* P1   = w + OFF_P1;
    u64*   pairs= (u64*)(w + OFF_PAIRS);

    float* outp = (float*)d_out;
    float* out0   = outp + DO_OUT;
    float* oscal  = outp + DO_RECON;
    float* idxf   = outp + DO_IDX;
    float* qout   = outp + DO_QUANT;

    hipMemsetAsync(slots, 0, 1536 * sizeof(float), stream);
    hipMemsetAsync(fc, 0, 2 * sizeof(int), stream);
    hipMemsetAsync(zerob, 0, 128 * sizeof(float), stream);

    setup_kernel<<<1024, 256, 0, stream>>>(We2, Wtd1, Wtd2, bd1, bd2, cbs,
                                           Be2, Bd1, Bd2, bx1, bx2, cbh, cbl, c2);

    const float* cb1p = cbs + (size_t)NTOK * CBD;

    // decoder stage-1 code tables: P = cb . Bd1^T
    gemm_nt<<<dim3(8, 2), 256, 0, stream>>>(cbs,  Bd1, zerob, P0, 1024, 128, 512, 0, 0);
    gemm_nt<<<dim3(8, 2), 256, 0, stream>>>(cb1p, Bd1, zerob, P1, 1024, 128, 512, 0, 0);

    // encoder
    enc1_kernel<<<(NB * T2L * HIDC) / 256, 256, 0, stream>>>(img, We1, be1, h1);
    gemm_nt<<<dim3(MTOK / 128, 1), 256, 0, stream>>>(h1, Be2, be2, h2, MTOK, 64, 128, 1, 1);
    gemm_nt<<<dim3(MTOK / 128, 8), 256, 0, stream>>>(h2, We3, be3, xr, MTOK, 512, 64, 0, 0);

    // residual VQ, q = 0 (no gather codepath)
    vq_bf16_top2<0><<<dim3(4, MTOK / 128), 256, 0, stream>>>(xr, cbh, cbl, c2, nullptr, nullptr, pairs);
    vq_reduce<<<MTOK / 256, 256, 0, stream>>>(pairs, keys, fc + 0, flag);
    vq_rescue<<<1024, 256, 0, stream>>>(xr, cbs, c2, nullptr, nullptr, fc + 0, flag, keys);
    // q = 1 (A = xr - cb0[i0] staged on the fly)
    vq_bf16_top2<1><<<dim3(4, MTOK / 128), 256, 0, stream>>>(xr, cbh + (size_t)NTOK * 512, cbl + (size_t)NTOK * 512,
                                                             c2 + NTOK, keys, cbs, pairs);
    vq_reduce<<<MTOK / 256, 256, 0, stream>>>(pairs, keys + MTOK, fc + 1, flag + MTOK);
    vq_rescue<<<1024, 256, 0, stream>>>(xr, cb1p, c2 + NTOK, cbs, keys, fc + 1, flag + MTOK, keys + MTOK);

    // fused: indices + commit losses + quantized output + d1 gather
    post_vq<<<dim3(NB, 7, 4), 256, 0, stream>>>(xr, cbs, cb1p, keys, keys + MTOK,
                                                P0, P1, bx1, idxf, idxi, qout, h1, slots);

    // decoder: fused convT2 + final conv + recon
    dec2_fused<<<M2TOK / 128, 256, 0, stream>>>(h1, Bd2, bx2, Wd3, bd3, img, out0, slots);

    finalize_kernel<<<1, 256, 0, stream>>>(slots, oscal);
}

// Round 14
// 1395.870 us; speedup vs baseline: 1.1342x; 1.1342x over previous
//
#include <hip/hip_runtime.h>

// ---------------- problem constants ----------------
#define NB    256
#define TLEN  1632
#define HIDC  64
#define CBD   512
#define NTOK  1024
#define T2L   816
#define T4L   408
#define MTOK  (NB*T4L)     // 104448
#define M2TOK (NB*T2L)     // 208896
#define MOUT  (NB*TLEN)    // 417792
#define TAU   0.05f

// d_out flat offsets (floats)
#define DO_OUT    ((size_t)0)
#define DO_RECON  ((size_t)417792)
#define DO_IDX    ((size_t)417795)
#define DO_QUANT  ((size_t)626691)

typedef unsigned short u16;
typedef unsigned long long u64;
typedef __attribute__((ext_vector_type(8))) short short8;
typedef __attribute__((ext_vector_type(4))) float f32x4;

// ---------------- workspace layout (float units) ----------------
static constexpr size_t OFF_XR  = 0;                         // MTOK*512 f32
static constexpr size_t OFF_H1  = OFF_XR + (size_t)MTOK*512;
static constexpr size_t OFF_H2  = OFF_H1 + (size_t)NB*T2L*64;
static constexpr size_t OFF_BE2 = OFF_H2 + (size_t)NB*T4L*64;
static constexpr size_t OFF_BD1 = OFF_BE2 + 8192;
static constexpr size_t OFF_BD2 = OFF_BD1 + 65536;
static constexpr size_t OFF_BX1 = OFF_BD2 + 8192;
static constexpr size_t OFF_BX2 = OFF_BX1 + 128;
static constexpr size_t OFF_ZB  = OFF_BX2 + 128;
static constexpr size_t OFF_C2  = OFF_ZB + 128;
static constexpr size_t OFF_SLOT= OFF_C2 + 2048;             // 1536 loss slots
static constexpr size_t OFF_IDXI= OFF_SLOT + 1536;
static constexpr size_t OFF_KEYS= OFF_IDXI + (size_t)MTOK*2;
static constexpr size_t OFF_FC  = OFF_KEYS + (size_t)MTOK*4;
static constexpr size_t OFF_FLAG= OFF_FC + 4;
static constexpr size_t OFF_CBH = OFF_FLAG + (size_t)MTOK*2; // 2048*512 u16
static constexpr size_t OFF_CBL = OFF_CBH + 524288;
static constexpr size_t OFF_P0  = OFF_CBL + 524288;
static constexpr size_t OFF_P1  = OFF_P0 + 131072;
static constexpr size_t OFF_PAIRS = OFF_P1 + 131072;         // MTOK*8 u64

// ---------------- helpers ----------------
__device__ inline u64 shfl_xor_u64_w16(u64 v, int m) {
    unsigned lo = (unsigned)v, hi = (unsigned)(v >> 32);
    lo = __shfl_xor(lo, m, 16);
    hi = __shfl_xor(hi, m, 16);
    return (((u64)hi) << 32) | lo;
}
__device__ inline u64 packkey(float d, int n) {
    unsigned u = __float_as_uint(d);
    u = (u & 0x80000000u) ? ~u : (u | 0x80000000u);
    return (((u64)u) << 32) | (unsigned)n;
}
__device__ inline float unpackd(u64 k) {
    unsigned u = (unsigned)(k >> 32);
    u = (u & 0x80000000u) ? (u & 0x7fffffffu) : ~u;
    return __uint_as_float(u);
}
__device__ inline void merge2(u64& k1, u64& k2, u64 o1, u64 o2) {
    u64 n1 = (k1 < o1) ? k1 : o1;
    u64 hi = (k1 < o1) ? o1 : k1;
    u64 cand = (k1 <= o1) ? k2 : o2;
    u64 n2 = (hi < cand) ? hi : cand;
    k1 = n1; k2 = n2;
}
__device__ inline void split4(float4 v, uint2& h, uint2& l) {
    unsigned b0 = __float_as_uint(v.x), b1 = __float_as_uint(v.y),
             b2 = __float_as_uint(v.z), b3 = __float_as_uint(v.w);
    float l0 = v.x - __uint_as_float(b0 & 0xFFFF0000u);
    float l1 = v.y - __uint_as_float(b1 & 0xFFFF0000u);
    float l2 = v.z - __uint_as_float(b2 & 0xFFFF0000u);
    float l3 = v.w - __uint_as_float(b3 & 0xFFFF0000u);
    h.x = (b0 >> 16) | (b1 & 0xFFFF0000u);
    h.y = (b2 >> 16) | (b3 & 0xFFFF0000u);
    l.x = (__float_as_uint(l0) >> 16) | (__float_as_uint(l1) & 0xFFFF0000u);
    l.y = (__float_as_uint(l2) >> 16) | (__float_as_uint(l3) & 0xFFFF0000u);
}

// ---------------- fused setup: weight prep + codebook split + codebook norms ----------------
__global__ void setup_kernel(const float* __restrict__ We2, const float* __restrict__ Wtd1,
                             const float* __restrict__ Wtd2, const float* __restrict__ bd1,
                             const float* __restrict__ bd2, const float* __restrict__ cbs,
                             float* __restrict__ Be2, float* __restrict__ Bd1,
                             float* __restrict__ Bd2, float* __restrict__ bx1, float* __restrict__ bx2,
                             u16* __restrict__ cbh, u16* __restrict__ cbl, float* __restrict__ c2) {
    size_t t = (size_t)blockIdx.x * 256 + threadIdx.x;   // grid 1024 -> 262144 threads
    {
        float4 v = *(const float4*)(cbs + t * 4);
        uint2 h, l; split4(v, h, l);
        *(uint2*)&cbh[t * 4] = h;
        *(uint2*)&cbl[t * 4] = l;
    }
    {
        int w = (int)(t >> 6);
        int lane = threadIdx.x & 63;
        if (w < 2048) {
            const float* r = cbs + (size_t)w * 512;
            float4 a = *(const float4*)(r + lane * 8);
            float4 b = *(const float4*)(r + lane * 8 + 4);
            float s = a.x*a.x + a.y*a.y + a.z*a.z + a.w*a.w + b.x*b.x + b.y*b.y + b.z*b.z + b.w*b.w;
            #pragma unroll
            for (int o = 32; o > 0; o >>= 1) s += __shfl_down(s, o, 64);
            if (lane == 0) c2[w] = s;
        }
    }
    size_t stride = (size_t)gridDim.x * 256;
    for (size_t x = t; x < 64 * 128; x += stride) {
        int c = (int)(x >> 7), k = (int)(x & 127);
        Be2[x] = We2[c * 128 + ((k & 63) << 1) + (k >> 6)];
    }
    for (size_t x = t; x < 128 * 512; x += stride) {
        int n = (int)(x >> 9), k = (int)(x & 511);
        Bd1[x] = Wtd1[k * 128 + n];
    }
    for (size_t x = t; x < 128 * 64; x += stride) {
        int n = (int)(x >> 6), k = (int)(x & 63);
        Bd2[x] = Wtd2[k * 128 + n];
    }
    for (size_t x = t; x < 128; x += stride) { bx1[x] = bd1[x >> 1]; bx2[x] = bd2[x >> 1]; }
}

// ---------------- encoder conv1 ----------------
__global__ void enc1_kernel(const float* __restrict__ img, const float* __restrict__ W,
                            const float* __restrict__ bias, float* __restrict__ h1) {
    int idx = blockIdx.x * 256 + threadIdx.x;
    int c = idx & 63;
    int t = (idx >> 6) % T2L;
    int b = idx / (64 * T2L);
    float v = W[c * 2] * img[(size_t)b * TLEN + 2 * t] +
              W[c * 2 + 1] * img[(size_t)b * TLEN + 2 * t + 1] + bias[c];
    h1[idx] = fmaxf(v, 0.f);
}

// ---------------- generic NT SGEMM (cmode0 only) ----------------
__global__ __launch_bounds__(256) void gemm_nt(const float* __restrict__ A, const float* __restrict__ Bw,
                        const float* __restrict__ bias, float* __restrict__ C,
                        int M, int N, int K, int amode, int relu) {
    __shared__ float As[32][132];
    __shared__ float Bs[32][68];
    int m0 = blockIdx.x * 128;
    int n0 = blockIdx.y * 64;
    int tid = threadIdx.x;
    int tx = tid & 15;
    int ty = tid >> 4;
    float acc[8][4];
    #pragma unroll
    for (int i = 0; i < 8; ++i)
        #pragma unroll
        for (int j = 0; j < 4; ++j) acc[i][j] = 0.f;

    for (int k0 = 0; k0 < K; k0 += 32) {
        #pragma unroll
        for (int i = 0; i < 4; ++i) {
            int idx = tid + i * 256;
            int row = idx >> 3;
            int kq = idx & 7;
            int m = m0 + row;
            size_t base;
            if (amode == 0) base = (size_t)m * K;
            else            base = (size_t)(((m / T4L) * T2L + 2 * (m % T4L)) * 64);
            float4 v = *(const float4*)(A + base + k0 + kq * 4);
            int kk = kq * 4;
            As[kk + 0][row] = v.x; As[kk + 1][row] = v.y;
            As[kk + 2][row] = v.z; As[kk + 3][row] = v.w;
        }
        #pragma unroll
        for (int i = 0; i < 2; ++i) {
            int idx = tid + i * 256;
            int row = idx >> 3;
            int kq = idx & 7;
            float4 v = *(const float4*)(Bw + (size_t)(n0 + row) * K + k0 + kq * 4);
            int kk = kq * 4;
            Bs[kk + 0][row] = v.x; Bs[kk + 1][row] = v.y;
            Bs[kk + 2][row] = v.z; Bs[kk + 3][row] = v.w;
        }
        __syncthreads();
        #pragma unroll
        for (int kk = 0; kk < 32; ++kk) {
            float a[8], bf[4];
            float4 a0 = *(const float4*)&As[kk][ty * 8];
            float4 a1 = *(const float4*)&As[kk][ty * 8 + 4];
            a[0]=a0.x; a[1]=a0.y; a[2]=a0.z; a[3]=a0.w;
            a[4]=a1.x; a[5]=a1.y; a[6]=a1.z; a[7]=a1.w;
            float4 b0 = *(const float4*)&Bs[kk][tx * 4];
            bf[0]=b0.x; bf[1]=b0.y; bf[2]=b0.z; bf[3]=b0.w;
            #pragma unroll
            for (int i = 0; i < 8; ++i)
                #pragma unroll
                for (int j = 0; j < 4; ++j) acc[i][j] += a[i] * bf[j];
        }
        __syncthreads();
    }
    #pragma unroll
    for (int i = 0; i < 8; ++i) {
        int m = m0 + ty * 8 + i;
        float4 v;
        v.x = acc[i][0] + bias[n0 + tx * 4 + 0];
        v.y = acc[i][1] + bias[n0 + tx * 4 + 1];
        v.z = acc[i][2] + bias[n0 + tx * 4 + 2];
        v.w = acc[i][3] + bias[n0 + tx * 4 + 3];
        if (relu) { v.x=fmaxf(v.x,0.f); v.y=fmaxf(v.y,0.f); v.z=fmaxf(v.z,0.f); v.w=fmaxf(v.w,0.f); }
        *(float4*)(C + (size_t)m * N + n0 + tx * 4) = v;
    }
}

// ---------------- VQ: block 128(M)x256(N), wave 64x128, split-bf16 MFMA, rr=0 ----------------
// Q1=0: plain A staging (no gather code/registers). Q1=1: A = xr - cb0[i0] on the fly.
// launch_bounds (256,2): ~220-VGPR working set; (256,3) spills (R10: 3GB scratch).
template<int Q1>
__global__ __launch_bounds__(256, 2) void vq_bf16_top2(
    const float* __restrict__ A, const u16* __restrict__ cbh, const u16* __restrict__ cbl,
    const float* __restrict__ c2, const u64* __restrict__ prevkeys, const float* __restrict__ cb0,
    u64* __restrict__ pairs)
{
    __shared__ u16 Ah[128 * 40], Al[128 * 40];
    __shared__ u16 Bh[256 * 40], Bl[256 * 40];
    int tid = threadIdx.x;
    int n0 = blockIdx.x * 256, m0 = blockIdx.y * 128;
    int lane = tid & 63, wid = tid >> 6;
    int lm = lane & 15, quad = lane >> 4;
    int wm = wid >> 1, wn = wid & 1;

    f32x4 acc[4][8];
    #pragma unroll
    for (int i = 0; i < 4; ++i)
        #pragma unroll
        for (int j = 0; j < 8; ++j) acc[i][j] = (f32x4){0.f, 0.f, 0.f, 0.f};

    int ar[4], acq[4];
    size_t coff[4];
    #pragma unroll
    for (int i = 0; i < 4; ++i) {
        int idx = tid + i * 256;
        ar[i] = idx >> 3; acq[i] = idx & 7;
        if (Q1) {
            int i0 = (int)(prevkeys[m0 + ar[i]] & 0xFFFFFFFFull);
            coff[i] = (size_t)i0 * 512;
        }
    }

    for (int k0 = 0; k0 < 512; k0 += 32) {
        float4 av[4];
        #pragma unroll
        for (int i = 0; i < 4; ++i) {
            av[i] = *(const float4*)(A + (size_t)(m0 + ar[i]) * 512 + k0 + acq[i] * 4);
            if (Q1) {
                float4 cv = *(const float4*)(cb0 + coff[i] + k0 + acq[i] * 4);
                av[i].x -= cv.x; av[i].y -= cv.y; av[i].z -= cv.z; av[i].w -= cv.w;
            }
        }
        short8 bv[8];
        int br[8], bcc[8], bpl[8];
        #pragma unroll
        for (int i = 0; i < 8; ++i) {
            int idx = tid + i * 256;
            br[i] = idx >> 3; int sub = idx & 7;
            bcc[i] = sub & 3; bpl[i] = sub >> 2;
            const u16* src = bpl[i] ? cbl : cbh;
            bv[i] = *(const short8*)(src + (size_t)(n0 + br[i]) * 512 + k0 + bcc[i] * 8);
        }
        __syncthreads();
        #pragma unroll
        for (int i = 0; i < 4; ++i) {
            uint2 h, l; split4(av[i], h, l);
            *(uint2*)&Ah[ar[i] * 40 + acq[i] * 4] = h;
            *(uint2*)&Al[ar[i] * 40 + acq[i] * 4] = l;
        }
        #pragma unroll
        for (int i = 0; i < 8; ++i) {
            u16* dst = bpl[i] ? Bl : Bh;
            *(short8*)&dst[br[i] * 40 + bcc[i] * 8] = bv[i];
        }
        __syncthreads();
        short8 ah[4], al_[4];
        #pragma unroll
        for (int mt = 0; mt < 4; ++mt) {
            int r = wm * 64 + mt * 16 + lm;
            ah[mt]  = *(const short8*)&Ah[r * 40 + quad * 8];
            al_[mt] = *(const short8*)&Al[r * 40 + quad * 8];
        }
        #pragma unroll
        for (int nt = 0; nt < 8; ++nt) {
            int rn = wn * 128 + nt * 16 + lm;
            short8 bh = *(const short8*)&Bh[rn * 40 + quad * 8];
            short8 bl = *(const short8*)&Bl[rn * 40 + quad * 8];
            #pragma unroll
            for (int mt = 0; mt < 4; ++mt) {
                acc[mt][nt] = __builtin_amdgcn_mfma_f32_16x16x32_bf16(al_[mt], bh, acc[mt][nt], 0, 0, 0);
                acc[mt][nt] = __builtin_amdgcn_mfma_f32_16x16x32_bf16(ah[mt], bl, acc[mt][nt], 0, 0, 0);
                acc[mt][nt] = __builtin_amdgcn_mfma_f32_16x16x32_bf16(ah[mt], bh, acc[mt][nt], 0, 0, 0);
            }
        }
    }
    float c2v[8];
    #pragma unroll
    for (int nt = 0; nt < 8; ++nt) c2v[nt] = c2[n0 + wn * 128 + nt * 16 + lm];

    __syncthreads();
    u64* scr = (u64*)Ah;   // [2 wn][128 tokens][2]
    #pragma unroll
    for (int mt = 0; mt < 4; ++mt) {
        #pragma unroll
        for (int rg = 0; rg < 4; ++rg) {
            int tl = wm * 64 + mt * 16 + quad * 4 + rg;
            u64 k1 = ~0ull, k2 = ~0ull;
            #pragma unroll
            for (int nt = 0; nt < 8; ++nt) {
                float d = c2v[nt] - 2.0f * acc[mt][nt][rg];
                u64 k = packkey(d, n0 + wn * 128 + nt * 16 + lm);
                if (k < k1) { k2 = k1; k1 = k; } else if (k < k2) { k2 = k; }
            }
            #pragma unroll
            for (int s = 1; s < 16; s <<= 1) {
                u64 o1 = shfl_xor_u64_w16(k1, s);
                u64 o2 = shfl_xor_u64_w16(k2, s);
                merge2(k1, k2, o1, o2);
            }
            if (lm == 0) { scr[wn * 256 + tl * 2] = k1; scr[wn * 256 + tl * 2 + 1] = k2; }
        }
    }
    __syncthreads();
    if (tid < 128) {
        u64 a1 = scr[tid * 2], a2 = scr[tid * 2 + 1];
        merge2(a1, a2, scr[256 + tid * 2], scr[256 + tid * 2 + 1]);
        size_t base = (size_t)(m0 + tid) * 8 + blockIdx.x * 2;
        pairs[base] = a1; pairs[base + 1] = a2;
    }
}

// ---------------- reduce: global top2 per token from 4 block-pairs ----------------
__global__ void vq_reduce(const u64* __restrict__ pairs, u64* __restrict__ keybuf,
                          int* __restrict__ fc, int* __restrict__ flaglist) {
    int m = blockIdx.x * 256 + threadIdx.x;
    const u64* p = pairs + (size_t)m * 8;
    u64 k1 = ~0ull, k2 = ~0ull;
    #pragma unroll
    for (int i = 0; i < 8; ++i) {
        u64 k = p[i];
        if (k < k1) { k2 = k1; k1 = k; } else if (k < k2) { k2 = k; }
    }
    keybuf[m] = k1;
    if (unpackd(k2) - unpackd(k1) < TAU) {
        int pos = atomicAdd(fc, 1);
        flaglist[pos] = m;
    }
}

// ---------------- rescue: exact fp32 argmin for flagged tokens (rr=0; q1 subtracts cb0[i0]) ----
__global__ void vq_rescue(const float* __restrict__ xr, const float* __restrict__ cb,
                          const float* __restrict__ c2, const float* __restrict__ cb0,
                          const u64* __restrict__ prevkeys,
                          const int* __restrict__ fc, const int* __restrict__ flaglist,
                          u64* __restrict__ keybuf) {
    __shared__ u64 red[4];
    int cnt = *fc;
    int lane = threadIdx.x & 63, wid = threadIdx.x >> 6;
    for (int f = blockIdx.x; f < cnt; f += gridDim.x) {
        int m = flaglist[f];
        float4 rv0 = *(const float4*)(xr + (size_t)m * 512 + lane * 8);
        float4 rv1 = *(const float4*)(xr + (size_t)m * 512 + lane * 8 + 4);
        if (cb0) {
            size_t co = (size_t)(prevkeys[m] & 0xFFFFFFFFull) * 512;
            float4 c0 = *(const float4*)(cb0 + co + lane * 8);
            float4 c1 = *(const float4*)(cb0 + co + lane * 8 + 4);
            rv0.x -= c0.x; rv0.y -= c0.y; rv0.z -= c0.z; rv0.w -= c0.w;
            rv1.x -= c1.x; rv1.y -= c1.y; rv1.z -= c1.z; rv1.w -= c1.w;
        }
        u64 best = ~0ull;
        for (int c = wid * 256; c < wid * 256 + 256; ++c) {
            const float* cp = cb + (size_t)c * 512 + lane * 8;
            float4 c0 = *(const float4*)cp;
            float4 c1 = *(const float4*)(cp + 4);
            float p = rv0.x*c0.x + rv0.y*c0.y + rv0.z*c0.z + rv0.w*c0.w
                    + rv1.x*c1.x + rv1.y*c1.y + rv1.z*c1.z + rv1.w*c1.w;
            #pragma unroll
            for (int s = 1; s < 64; s <<= 1) p += __shfl_xor(p, s, 64);
            u64 k = packkey(c2[c] - 2.0f * p, c);
            if (k < best) best = k;
        }
        if (lane == 0) red[wid] = best;
        __syncthreads();
        if (threadIdx.x == 0) {
            u64 b = red[0];
            if (red[1] < b) b = red[1];
            if (red[2] < b) b = red[2];
            if (red[3] < b) b = red[3];
            keybuf[m] = b;
        }
        __syncthreads();
    }
}

// ---------------- commit + indices (wave per token, exact fp32 losses) ----------------
__global__ void commit_idx_kernel(const float* __restrict__ xr,
                                  const float* __restrict__ cb0f, const float* __restrict__ cb1f,
                                  const u64* __restrict__ keys0, const u64* __restrict__ keys1,
                                  float* __restrict__ idx_f, int* __restrict__ idx_i,
                                  float* __restrict__ slots) {
    int tid = threadIdx.x;
    int lane = tid & 63;
    int m = blockIdx.x * 4 + (tid >> 6);
    unsigned i0 = (unsigned)(keys0[m] & 0xFFFFFFFFull);
    unsigned i1 = (unsigned)(keys1[m] & 0xFFFFFFFFull);
    const float* x = xr + (size_t)m * 512 + lane * 8;
    const float* c0 = cb0f + (size_t)i0 * 512 + lane * 8;
    const float* c1 = cb1f + (size_t)i1 * 512 + lane * 8;
    float4 x0 = *(const float4*)x, x1 = *(const float4*)(x + 4);
    float4 a0 = *(const float4*)c0, a1 = *(const float4*)(c0 + 4);
    float4 b0 = *(const float4*)c1, b1 = *(const float4*)(c1 + 4);
    x0.x -= a0.x; x0.y -= a0.y; x0.z -= a0.z; x0.w -= a0.w;
    x1.x -= a1.x; x1.y -= a1.y; x1.z -= a1.z; x1.w -= a1.w;
    float s1 = x0.x*x0.x + x0.y*x0.y + x0.z*x0.z + x0.w*x0.w
             + x1.x*x1.x + x1.y*x1.y + x1.z*x1.z + x1.w*x1.w;
    x0.x -= b0.x; x0.y -= b0.y; x0.z -= b0.z; x0.w -= b0.w;
    x1.x -= b1.x; x1.y -= b1.y; x1.z -= b1.z; x1.w -= b1.w;
    float s2 = x0.x*x0.x + x0.y*x0.y + x0.z*x0.z + x0.w*x0.w
             + x1.x*x1.x + x1.y*x1.y + x1.z*x1.z + x1.w*x1.w;
    #pragma unroll
    for (int o = 32; o > 0; o >>= 1) { s1 += __shfl_down(s1, o, 64); s2 += __shfl_down(s2, o, 64); }
    if (lane == 0) {
        atomicAdd(&slots[512 + (m & 511)], s1);
        atomicAdd(&slots[1024 + (m & 511)], s2);
        idx_f[(size_t)m * 2]     = (float)i0;
        idx_f[(size_t)m * 2 + 1] = (float)i1;
        idx_i[m * 2] = (int)i0;
        idx_i[m * 2 + 1] = (int)i1;
    }
}

// ---------------- quantized output (channel-major) via LDS transpose ----------------
__global__ void quant_out_kernel(const float* __restrict__ cb0, const float* __restrict__ cb1,
                                 const int* __restrict__ idxi, float* __restrict__ out4) {
    __shared__ float buf[64][129];
    __shared__ int i0s[64], i1s[64];
    int b = blockIdx.x;
    int t0 = blockIdx.y * 64;
    int c0 = blockIdx.z * 128;
    int tid = threadIdx.x;
    if (tid < 64) {
        int t = t0 + tid;
        int i0 = 0, i1 = 0;
        if (t < T4L) { i0 = idxi[(b * T4L + t) * 2]; i1 = idxi[(b * T4L + t) * 2 + 1]; }
        i0s[tid] = i0; i1s[tid] = i1;
    }
    __syncthreads();
    int cl = tid & 127, th = tid >> 7;
    for (int t = th; t < 64; t += 2) {
        if (t0 + t < T4L)
            buf[t][cl] = cb0[(size_t)i0s[t] * 512 + c0 + cl] + cb1[(size_t)i1s[t] * 512 + c0 + cl];
    }
    __syncthreads();
    int lane = tid & 63, ch = tid >> 6;
    for (int cc = ch; cc < 128; cc += 4) {
        int t = t0 + lane;
        if (t < T4L) out4[((size_t)b * 512 + c0 + cc) * T4L + t] = buf[lane][cc];
    }
}

// ---------------- decoder stage-1 via code tables ----------------
__global__ void d1_gather_kernel(const float* __restrict__ P0, const float* __restrict__ P1,
                                 const int* __restrict__ idxi, const float* __restrict__ bx1,
                                 float* __restrict__ d1) {
    int x = blockIdx.x * 256 + threadIdx.x;
    int n = x & 127;
    int m = x >> 7;
    int b = m / T4L, t = m % T4L;
    int i0 = idxi[m * 2], i1 = idxi[m * 2 + 1];
    float v = P0[i0 * 128 + n] + P1[i1 * 128 + n] + bx1[n];
    v = fmaxf(v, 0.f);
    d1[((size_t)(b * T2L + 2 * t + (n & 1))) * 64 + (n >> 1)] = v;
}

// ---------------- fused convT2 + final 1x1 conv + recon loss ----------------
__global__ __launch_bounds__(256) void dec2_fused(
    const float* __restrict__ d1, const float* __restrict__ Bd2, const float* __restrict__ bx2,
    const float* __restrict__ W3, const float* __restrict__ b3, const float* __restrict__ img,
    float* __restrict__ out, float* __restrict__ slots)
{
    __shared__ float As[32][132];
    __shared__ float Bs[32][132];
    __shared__ float w3s[64];
    int m0 = blockIdx.x * 128;
    int tid = threadIdx.x;
    int tx = tid & 15;
    int ty = tid >> 4;
    if (tid < 64) w3s[tid] = W3[tid];
    float acc[8][8];
    #pragma unroll
    for (int i = 0; i < 8; ++i)
        #pragma unroll
        for (int j = 0; j < 8; ++j) acc[i][j] = 0.f;

    for (int k0 = 0; k0 < 64; k0 += 32) {
        #pragma unroll
        for (int i = 0; i < 4; ++i) {
            int idx = tid + i * 256;
            int row = idx >> 3;
            int kq = idx & 7;
            float4 v = *(const float4*)(d1 + (size_t)(m0 + row) * 64 + k0 + kq * 4);
            int kk = kq * 4;
            As[kk + 0][row] = v.x; As[kk + 1][row] = v.y;
            As[kk + 2][row] = v.z; As[kk + 3][row] = v.w;
        }
        #pragma unroll
        for (int i = 0; i < 4; ++i) {
            int idx = tid + i * 256;
            int row = idx >> 3;
            int kq = idx & 7;
            float4 v = *(const float4*)(Bd2 + (size_t)row * 64 + k0 + kq * 4);
            int kk = kq * 4;
            Bs[kk + 0][row] = v.x; Bs[kk + 1][row] = v.y;
            Bs[kk + 2][row] = v.z; Bs[kk + 3][row] = v.w;
        }
        __syncthreads();
        #pragma unroll
        for (int kk = 0; kk < 32; ++kk) {
            float a[8], bf[8];
            float4 a0 = *(const float4*)&As[kk][ty * 8];
            float4 a1 = *(const float4*)&As[kk][ty * 8 + 4];
            a[0]=a0.x; a[1]=a0.y; a[2]=a0.z; a[3]=a0.w;
            a[4]=a1.x; a[5]=a1.y; a[6]=a1.z; a[7]=a1.w;
            float4 b0 = *(const float4*)&Bs[kk][tx * 4];
            float4 b1 = *(const float4*)&Bs[kk][64 + tx * 4];
            bf[0]=b0.x; bf[1]=b0.y; bf[2]=b0.z; bf[3]=b0.w;
            bf[4]=b1.x; bf[5]=b1.y; bf[6]=b1.z; bf[7]=b1.w;
            #pragma unroll
            for (int i = 0; i < 8; ++i)
                #pragma unroll
                for (int j = 0; j < 8; ++j) acc[i][j] += a[i] * bf[j];
        }
        __syncthreads();
    }
    float bb3 = b3[0];
    float local = 0.f;
    #pragma unroll
    for (int i = 0; i < 8; ++i) {
        float s0 = 0.f, s1 = 0.f;
        #pragma unroll
        for (int j = 0; j < 4; ++j) {
            int n = tx * 4 + j;
            float v = fmaxf(acc[i][j] + bx2[n], 0.f);
            float w = w3s[n >> 1];
            if (j & 1) s1 += w * v; else s0 += w * v;
            int n2 = 64 + tx * 4 + j;
            float v2 = fmaxf(acc[i][j + 4] + bx2[n2], 0.f);
            float w2 = w3s[n2 >> 1];
            if (j & 1) s1 += w2 * v2; else s0 += w2 * v2;
        }
        #pragma unroll
        for (int o = 8; o > 0; o >>= 1) { s0 += __shfl_down(s0, o, 16); s1 += __shfl_down(s1, o, 16); }
        if (tx == 0) {
            int m = m0 + ty * 8 + i;
            int b = m / T2L, t2 = m % T2L;
            size_t o0 = (size_t)b * TLEN + 2 * t2;
            float v0 = s0 + bb3, v1 = s1 + bb3;
            out[o0] = v0; out[o0 + 1] = v1;
            float e0 = img[o0] - v0, e1 = img[o0 + 1] - v1;
            local += e0 * e0 + e1 * e1;
        }
    }
    if (tx == 0) atomicAdd(&slots[(blockIdx.x * 16 + ty) & 511], local);
}

// ---------------- finalize losses ----------------
__global__ void finalize_kernel(const float* __restrict__ slots, float* __restrict__ out_scalars) {
    __shared__ float red[256];
    int tid = threadIdx.x;
    for (int which = 0; which < 3; ++which) {
        float s = slots[which * 512 + tid] + slots[which * 512 + tid + 256];
        red[tid] = s; __syncthreads();
        for (int st = 128; st > 0; st >>= 1) { if (tid < st) red[tid] += red[tid + st]; __syncthreads(); }
        if (tid == 0) {
            float denom = (which == 0) ? (float)MOUT : (float)((size_t)MTOK * 512);
            out_scalars[which] = red[0] / denom;
        }
        __syncthreads();
    }
}

// ---------------- launch ----------------
extern "C" void kernel_launch(void* const* d_in, const int* in_sizes, int n_in,
                              void* d_out, int out_size, void* d_ws, size_t ws_size,
                              hipStream_t stream) {
    const float* img  = (const float*)d_in[0];
    const float* We1  = (const float*)d_in[1];
    const float* be1  = (const float*)d_in[2];
    const float* We2  = (const float*)d_in[3];
    const float* be2  = (const float*)d_in[4];
    const float* We3  = (const float*)d_in[5];
    const float* be3  = (const float*)d_in[6];
    const float* cbs  = (const float*)d_in[7];
    const float* Wtd1 = (const float*)d_in[8];
    const float* bd1  = (const float*)d_in[9];
    const float* Wtd2 = (const float*)d_in[10];
    const float* bd2  = (const float*)d_in[11];
    const float* Wd3  = (const float*)d_in[12];
    const float* bd3  = (const float*)d_in[13];

    float* w = (float*)d_ws;
    float* xr   = w + OFF_XR;
    float* h1   = w + OFF_H1;
    float* h2   = w + OFF_H2;
    float* Be2  = w + OFF_BE2;
    float* Bd1  = w + OFF_BD1;
    float* Bd2  = w + OFF_BD2;
    float* bx1  = w + OFF_BX1;
    float* bx2  = w + OFF_BX2;
    float* zerob= w + OFF_ZB;
    float* c2   = w + OFF_C2;
    float* slots= w + OFF_SLOT;
    int*   idxi = (int*)(w + OFF_IDXI);
    u64*   keys = (u64*)(w + OFF_KEYS);
    int*   fc   = (int*)(w + OFF_FC);
    int*   flag = (int*)(w + OFF_FLAG);
    u16*   cbh  = (u16*)(w + OFF_CBH);
    u16*   cbl  = (u16*)(w + OFF_CBL);
    float* P0   = w + OFF_P0;
    float* P1   = w + OFF_P1;
    u64*   pairs= (u64*)(w + OFF_PAIRS);

    float* outp = (float*)d_out;
    float* out0   = outp + DO_OUT;
    float* oscal  = outp + DO_RECON;
    float* idxf   = outp + DO_IDX;
    float* qout   = outp + DO_QUANT;

    hipMemsetAsync(slots, 0, 1536 * sizeof(float), stream);
    hipMemsetAsync(fc, 0, 2 * sizeof(int), stream);
    hipMemsetAsync(zerob, 0, 128 * sizeof(float), stream);

    setup_kernel<<<1024, 256, 0, stream>>>(We2, Wtd1, Wtd2, bd1, bd2, cbs,
                                           Be2, Bd1, Bd2, bx1, bx2, cbh, cbl, c2);

    const float* cb1p = cbs + (size_t)NTOK * CBD;

    // decoder stage-1 code tables: P = cb . Bd1^T
    gemm_nt<<<dim3(8, 2), 256, 0, stream>>>(cbs,  Bd1, zerob, P0, 1024, 128, 512, 0, 0);
    gemm_nt<<<dim3(8, 2), 256, 0, stream>>>(cb1p, Bd1, zerob, P1, 1024, 128, 512, 0, 0);

    // encoder
    enc1_kernel<<<(NB * T2L * HIDC) / 256, 256, 0, stream>>>(img, We1, be1, h1);
    gemm_nt<<<dim3(MTOK / 128, 1), 256, 0, stream>>>(h1, Be2, be2, h2, MTOK, 64, 128, 1, 1);
    gemm_nt<<<dim3(MTOK / 128, 8), 256, 0, stream>>>(h2, We3, be3, xr, MTOK, 512, 64, 0, 0);

    // residual VQ, q = 0 (no gather codepath)
    vq_bf16_top2<0><<<dim3(4, MTOK / 128), 256, 0, stream>>>(xr, cbh, cbl, c2, nullptr, nullptr, pairs);
    vq_reduce<<<MTOK / 256, 256, 0, stream>>>(pairs, keys, fc + 0, flag);
    vq_rescue<<<1024, 256, 0, stream>>>(xr, cbs, c2, nullptr, nullptr, fc + 0, flag, keys);
    // q = 1 (A = xr - cb0[i0] staged on the fly)
    vq_bf16_top2<1><<<dim3(4, MTOK / 128), 256, 0, stream>>>(xr, cbh + (size_t)NTOK * 512, cbl + (size_t)NTOK * 512,
                                                             c2 + NTOK, keys, cbs, pairs);
    vq_reduce<<<MTOK / 256, 256, 0, stream>>>(pairs, keys + MTOK, fc + 1, flag + MTOK);
    vq_rescue<<<1024, 256, 0, stream>>>(xr, cb1p, c2 + NTOK, cbs, keys, fc + 1, flag + MTOK, keys + MTOK);

    // indices + exact commit losses
    commit_idx_kernel<<<MTOK / 4, 256, 0, stream>>>(xr, cbs, cb1p, keys, keys + MTOK, idxf, idxi, slots);

    // quantized output [B,512,408]
    quant_out_kernel<<<dim3(NB, 7, 4), 256, 0, stream>>>(cbs, cb1p, idxi, qout);

    // decoder: d1 from code tables, then fused convT2+final+recon
    d1_gather_kernel<<<(MTOK * 128) / 256, 256, 0, stream>>>(P0, P1, idxi, bx1, h1);
    dec2_fused<<<M2TOK / 128, 256, 0, stream>>>(h1, Bd2, bx2, Wd3, bd3, img, out0, slots);

    finalize_kernel<<<1, 256, 0, stream>>>(slots, oscal);
}